// Round 5
// baseline (280.467 us; speedup 1.0000x reference)
//
#include <hip/hip_runtime.h>

#define NN 10000      // nodes

typedef __attribute__((ext_vector_type(8))) short short8;
typedef __attribute__((ext_vector_type(4))) float f32x4;

__device__ __forceinline__ ushort f2b(float f) {
    union { float f; uint32_t u; } v; v.f = f;
    uint32_t u = v.u;
    return (ushort)((u + 0x7fffu + ((u >> 16) & 1u)) >> 16);
}
__device__ __forceinline__ uint packbf(float a, float b) {
    return (uint)f2b(a) | ((uint)f2b(b) << 16);
}
__device__ __forceinline__ float blo(uint u) {
    union { uint u; float f; } v; v.u = u << 16; return v.f;
}
__device__ __forceinline__ float bhi(uint u) {
    union { uint u; float f; } v; v.u = u & 0xffff0000u; return v.f;
}

// ---------------------------------------------------------------------------
// CSR build kernels (proven)
// ---------------------------------------------------------------------------
__global__ __launch_bounds__(256) void zero_int(int* __restrict__ p, int n) {
    int i = blockIdx.x * 256 + threadIdx.x;
    if (i < n) p[i] = 0;
}

__global__ __launch_bounds__(256) void count_dst(const int* __restrict__ dst,
                                                 int* __restrict__ counts, int E) {
    int i = blockIdx.x * 256 + threadIdx.x;
    if (i < E) atomicAdd(&counts[dst[i]], 1);
}

__global__ __launch_bounds__(1024) void scan_build(const int* __restrict__ counts,
                                                   int* __restrict__ offsets,
                                                   int* __restrict__ cursor,
                                                   float* __restrict__ inv_cnt, int n) {
    __shared__ int part[1024];
    int tid = threadIdx.x;
    int per = (n + 1023) / 1024;
    int base = tid * per;
    int s = 0;
    for (int i = 0; i < per; i++) { int idx = base + i; if (idx < n) s += counts[idx]; }
    part[tid] = s;
    __syncthreads();
    for (int off = 1; off < 1024; off <<= 1) {
        int v = (tid >= off) ? part[tid - off] : 0;
        __syncthreads();
        part[tid] += v;
        __syncthreads();
    }
    int run = (tid > 0) ? part[tid - 1] : 0;
    for (int i = 0; i < per; i++) {
        int idx = base + i;
        if (idx < n) {
            int c = counts[idx];
            offsets[idx] = run;
            cursor[idx]  = run;
            inv_cnt[idx] = 1.0f / fmaxf((float)c, 1.0f);
            run += c;
        }
    }
}

__global__ __launch_bounds__(256) void scatter_edges(const int* __restrict__ src,
                                                     const int* __restrict__ dst,
                                                     int* __restrict__ cursor,
                                                     int* __restrict__ sorted_src, int E) {
    int i = blockIdx.x * 256 + threadIdx.x;
    if (i < E) {
        int p = atomicAdd(&cursor[dst[i]], 1);
        sorted_src[p] = src[i];
    }
}

// ---------------------------------------------------------------------------
// Conversions. xcat row layout: [0:512) = xagg (bf16), [512:1024) = x (bf16).
// ---------------------------------------------------------------------------
__global__ __launch_bounds__(256) void cvt_x(const float* __restrict__ in,
                                             ushort* __restrict__ xcat, int n4) {
    int i = blockIdx.x * 256 + threadIdx.x;
    if (i >= n4) return;
    int idx = i * 4;
    int node = idx >> 9;         // din = 512
    int col  = idx & 511;
    float4 v = *(const float4*)(in + (size_t)node * 512 + col);
    uint2 p;
    p.x = packbf(v.x, v.y);
    p.y = packbf(v.z, v.w);
    *(uint2*)(xcat + (size_t)node * 1024 + 512 + col) = p;
}

// All three weight sets -> one bf16 buffer.
// Wcat layout: [0, 512) rows layer0, [512,1024) layer1, [1024,1280) layer2;
// each row 1024 wide: [0:512)=Wl[r], [512:1024)=Wr[r].
__global__ __launch_bounds__(256) void cvt_w_all(const float* __restrict__ Wl0,
                                                 const float* __restrict__ Wr0,
                                                 const float* __restrict__ Wl1,
                                                 const float* __restrict__ Wr1,
                                                 const float* __restrict__ Wl2,
                                                 const float* __restrict__ Wr2,
                                                 ushort* __restrict__ out, int n4) {
    int i = blockIdx.x * 256 + threadIdx.x;
    if (i >= n4) return;
    int idx = i * 4;                 // ushort index, [0, 1310720)
    int row = idx >> 10;             // global row 0..1279
    int col = idx & 1023;
    const float* Wl; const float* Wr; int r;
    if (row < 512)       { Wl = Wl0; Wr = Wr0; r = row; }
    else if (row < 1024) { Wl = Wl1; Wr = Wr1; r = row - 512; }
    else                 { Wl = Wl2; Wr = Wr2; r = row - 1024; }
    const float* src = (col < 512) ? (Wl + (size_t)r * 512 + col)
                                   : (Wr + (size_t)r * 512 + col - 512);
    float4 v = *(const float4*)src;
    uint2 p;
    p.x = packbf(v.x, v.y);
    p.y = packbf(v.z, v.w);
    *(uint2*)(out + idx) = p;
}

// ---------------------------------------------------------------------------
// Pre-GEMM mean aggregation over CSR neighbors, bf16 in / fp32 acc / bf16 out.
// One wave per node; lane covers 16B (8 bf16) of the 512-wide feature.
// Reads xcat right half (x), writes xcat left half (xagg). Edge loop x8.
// Also zeroes rowss for this layer's gemm (16 entries per block).
// ---------------------------------------------------------------------------
__global__ __launch_bounds__(256) void agg_mean(ushort* __restrict__ xcat,
                                                const int* __restrict__ offsets,
                                                const int* __restrict__ counts,
                                                const int* __restrict__ sorted_src,
                                                const float* __restrict__ inv_cnt,
                                                float* __restrict__ rowss, int n) {
    if (threadIdx.x < 16) {
        int z = blockIdx.x * 16 + (int)threadIdx.x;
        if (z < n) rowss[z] = 0.f;
    }
    int wave = threadIdx.x >> 6;
    int lane = threadIdx.x & 63;
    int node = blockIdx.x * 4 + wave;
    if (node >= n) return;
    int start = offsets[node];
    int cnt   = counts[node];
    float inv = inv_cnt[node];

    const uint* xr = (const uint*)xcat + 256;   // right half, uint units (row stride 512)
    int l4 = lane * 4;

    float acc[8];
#pragma unroll
    for (int k = 0; k < 8; k++) acc[k] = 0.f;

#define ACC8(v) do { \
    acc[0] += blo(v.x); acc[1] += bhi(v.x); \
    acc[2] += blo(v.y); acc[3] += bhi(v.y); \
    acc[4] += blo(v.z); acc[5] += bhi(v.z); \
    acc[6] += blo(v.w); acc[7] += bhi(v.w); } while (0)

    int e = 0;
    for (; e + 8 <= cnt; e += 8) {
        int s[8];
#pragma unroll
        for (int u = 0; u < 8; u++) s[u] = sorted_src[start + e + u];
        uint4 v[8];
#pragma unroll
        for (int u = 0; u < 8; u++) v[u] = *(const uint4*)(xr + (size_t)s[u] * 512 + l4);
#pragma unroll
        for (int u = 0; u < 8; u++) ACC8(v[u]);
    }
    for (; e < cnt; e++) {
        int s0 = sorted_src[start + e];
        uint4 v0 = *(const uint4*)(xr + (size_t)s0 * 512 + l4);
        ACC8(v0);
    }
#undef ACC8

    uint4 o;
    o.x = packbf(acc[0] * inv, acc[1] * inv);
    o.y = packbf(acc[2] * inv, acc[3] * inv);
    o.z = packbf(acc[4] * inv, acc[5] * inv);
    o.w = packbf(acc[6] * inv, acc[7] * inv);
    *(uint4*)(xcat + (size_t)node * 1024 + lane * 8) = o;
}

// ---------------------------------------------------------------------------
// bf16 MFMA NT-GEMM + fused epilogue:
//   C = A[M,1024] * B[Nn,1024]^T (+bias per col), stored bf16;
//   per-row sum of squares accumulated into rowss via atomicAdd.
// BM=64, BN=128, BK=32. 4 waves in 2x2 (32 rows x 64 cols each), acc[2][4].
// global_load_lds width-16 staging; XOR slot swizzle (R1-verified algebra).
// ---------------------------------------------------------------------------
__global__ __launch_bounds__(256) void gemm_mfma(const ushort* __restrict__ A,
                                                 const ushort* __restrict__ B,
                                                 const float* __restrict__ bias,
                                                 ushort* __restrict__ Cb,
                                                 float* __restrict__ rowss,
                                                 int M, int Nn) {
    __shared__ ushort Asl[64 * 32];    // 4 KB
    __shared__ ushort Bsl[128 * 32];   // 8 KB
    const int tid  = threadIdx.x;
    const int w    = tid >> 6;
    const int lane = tid & 63;
    const int bm = blockIdx.y * 64, bn = blockIdx.x * 128;
    const int wm = (w & 1) * 32, wn = (w >> 1) * 64;
    const int row16 = lane & 15, q = lane >> 4;

    f32x4 acc[2][4];
#pragma unroll
    for (int i = 0; i < 2; i++)
#pragma unroll
        for (int j = 0; j < 4; j++) acc[i][j] = (f32x4){0.f, 0.f, 0.f, 0.f};

    const int sc_r = lane >> 2;                  // row within 16-row chunk
    const int sc_s = lane & 3;                   // physical 16B slot
    const int koff = sc_s ^ ((sc_r >> 1) & 3);   // logical k-chunk in this slot
    const int swz  = (row16 >> 1) & 3;

    for (int k0 = 0; k0 < 1024; k0 += 32) {
        // A chunk w: rows [w*16, w*16+16)
        {
            int rloc = w * 16 + sc_r;
            int grow = bm + rloc; grow = grow < M ? grow : M - 1;
            const ushort* gp = A + (size_t)grow * 1024 + k0 + koff * 8;
            __builtin_amdgcn_global_load_lds(
                (const __attribute__((address_space(1))) uint32_t*)gp,
                (__attribute__((address_space(3))) uint32_t*)&Asl[w * 512],
                16, 0, 0);
        }
        // B chunks 2w, 2w+1
#pragma unroll
        for (int c = 0; c < 2; c++) {
            int chunk = w * 2 + c;
            int rloc  = chunk * 16 + sc_r;
            const ushort* gp = B + (size_t)(bn + rloc) * 1024 + k0 + koff * 8;
            __builtin_amdgcn_global_load_lds(
                (const __attribute__((address_space(1))) uint32_t*)gp,
                (__attribute__((address_space(3))) uint32_t*)&Bsl[chunk * 512],
                16, 0, 0);
        }
        __syncthreads();

        short8 af[2], bfr[4];
        int s = q ^ swz;
#pragma unroll
        for (int i = 0; i < 2; i++) {
            int r = wm + i * 16 + row16;
            af[i] = *(const short8*)&Asl[r * 32 + s * 8];
        }
#pragma unroll
        for (int j = 0; j < 4; j++) {
            int rn = wn + j * 16 + row16;
            bfr[j] = *(const short8*)&Bsl[rn * 32 + s * 8];
        }
#pragma unroll
        for (int i = 0; i < 2; i++)
#pragma unroll
            for (int j = 0; j < 4; j++)
                acc[i][j] = __builtin_amdgcn_mfma_f32_16x16x32_bf16(
                    af[i], bfr[j], acc[i][j], 0, 0, 0);
        __syncthreads();
    }

    // Epilogue. C/D layout: col = lane&15, row = (lane>>4)*4 + reg [m89-verified]
    float bias_v[4];
#pragma unroll
    for (int j = 0; j < 4; j++) bias_v[j] = bias[bn + wn + row16 + j * 16];

#pragma unroll
    for (int i = 0; i < 2; i++) {
#pragma unroll
        for (int r2 = 0; r2 < 4; r2++) {
            int row = bm + wm + i * 16 + q * 4 + r2;
            float v0 = acc[i][0][r2] + bias_v[0];
            float v1 = acc[i][1][r2] + bias_v[1];
            float v2 = acc[i][2][r2] + bias_v[2];
            float v3 = acc[i][3][r2] + bias_v[3];
            float ssp = v0 * v0 + v1 * v1 + v2 * v2 + v3 * v3;
            // reduce across the 16 lanes (row16 groups) holding this row
            ssp += __shfl_xor(ssp, 1, 64);
            ssp += __shfl_xor(ssp, 2, 64);
            ssp += __shfl_xor(ssp, 4, 64);
            ssp += __shfl_xor(ssp, 8, 64);
            if (row < M) {
                ushort* Cp = Cb + (size_t)row * Nn + bn + wn + row16;
                Cp[0]  = f2b(v0);
                Cp[16] = f2b(v1);
                Cp[32] = f2b(v2);
                Cp[48] = f2b(v3);
                if (row16 == 0) atomicAdd(&rowss[row], ssp);
            }
        }
    }
}

// ---------------------------------------------------------------------------
// apply_scale: x = relu(Cb * rsqrt(rowss)) — bf16 out (next layer) or fp32 out.
// One wave per node.
// ---------------------------------------------------------------------------
template <int DOUT, bool FINAL>
__global__ __launch_bounds__(256) void apply_scale(const ushort* __restrict__ Cb,
                                                   const float* __restrict__ rowss,
                                                   ushort* __restrict__ xcat,
                                                   float* __restrict__ outf, int n) {
    int wave = threadIdx.x >> 6;
    int lane = threadIdx.x & 63;
    int node = blockIdx.x * 4 + wave;
    if (node >= n) return;
    float scale = 1.0f / fmaxf(sqrtf(rowss[node]), 1e-12f);

    if (DOUT == 512) {
        uint4 v = *(const uint4*)(Cb + (size_t)node * 512 + lane * 8);
        float r0 = fmaxf(blo(v.x) * scale, 0.f), r1 = fmaxf(bhi(v.x) * scale, 0.f);
        float r2 = fmaxf(blo(v.y) * scale, 0.f), r3 = fmaxf(bhi(v.y) * scale, 0.f);
        float r4 = fmaxf(blo(v.z) * scale, 0.f), r5 = fmaxf(bhi(v.z) * scale, 0.f);
        float r6 = fmaxf(blo(v.w) * scale, 0.f), r7 = fmaxf(bhi(v.w) * scale, 0.f);
        uint4 o;
        o.x = packbf(r0, r1); o.y = packbf(r2, r3);
        o.z = packbf(r4, r5); o.w = packbf(r6, r7);
        *(uint4*)(xcat + (size_t)node * 1024 + 512 + lane * 8) = o;
    } else {
        uint2 v = *(const uint2*)(Cb + (size_t)node * 256 + lane * 4);
        float4 o;
        o.x = fmaxf(blo(v.x) * scale, 0.f);
        o.y = fmaxf(bhi(v.x) * scale, 0.f);
        o.z = fmaxf(blo(v.y) * scale, 0.f);
        o.w = fmaxf(bhi(v.y) * scale, 0.f);
        *(float4*)(outf + (size_t)node * 256 + lane * 4) = o;
    }
}

// ---------------------------------------------------------------------------
extern "C" void kernel_launch(void* const* d_in, const int* in_sizes, int n_in,
                              void* d_out, int out_size, void* d_ws, size_t ws_size,
                              hipStream_t stream) {
    const float* x    = (const float*)d_in[0];
    const int*   edge = (const int*)d_in[1];     // [2, E]: src row then dst row
    const float* Wl0  = (const float*)d_in[2];
    const float* b0   = (const float*)d_in[3];
    const float* Wr0  = (const float*)d_in[4];
    const float* Wl1  = (const float*)d_in[5];
    const float* b1   = (const float*)d_in[6];
    const float* Wr1  = (const float*)d_in[7];
    const float* Wl2  = (const float*)d_in[8];
    const float* b2   = (const float*)d_in[9];
    const float* Wr2  = (const float*)d_in[10];

    const int E = in_sizes[1] / 2;

    // Workspace layout (bytes)
    char* ws = (char*)d_ws;
    int*    counts  = (int*)(ws + 0);              // 40000
    int*    offsets = (int*)(ws + 40960);
    int*    cursor  = (int*)(ws + 81920);
    float*  invc    = (float*)(ws + 122880);
    int*    sorted  = (int*)(ws + 163840);         // 640000
    ushort* Wcat    = (ushort*)(ws + 804864);      // 1280*1024*2 = 2621440
    ushort* xcat    = (ushort*)(ws + 3426304);     // 10000*1024*2 = 20480000
    ushort* Cb      = (ushort*)(ws + 23906304);    // 10000*512*2  = 10240000
    float*  rowss   = (float*)(ws + 34146304);     // 40000
    // end: 34186304 bytes

    ushort* Wc0 = Wcat;
    ushort* Wc1 = Wcat + 512 * 1024;
    ushort* Wc2 = Wcat + 1024 * 1024;

    // ---- CSR build ----
    zero_int<<<(NN + 255) / 256, 256, 0, stream>>>(counts, NN);
    count_dst<<<(E + 255) / 256, 256, 0, stream>>>(edge + E, counts, E);
    scan_build<<<1, 1024, 0, stream>>>(counts, offsets, cursor, invc, NN);
    scatter_edges<<<(E + 255) / 256, 256, 0, stream>>>(edge, edge + E, cursor, sorted, E);

    // ---- bf16 conversions ----
    cvt_x<<<(NN * 512 / 4 + 255) / 256, 256, 0, stream>>>(x, xcat, NN * 512 / 4);
    cvt_w_all<<<(1280 * 1024 / 4 + 255) / 256, 256, 0, stream>>>(
        Wl0, Wr0, Wl1, Wr1, Wl2, Wr2, Wcat, 1280 * 1024 / 4);

    const int gyM = (NN + 63) / 64;    // 157
    const int gb  = (NN + 3) / 4;      // 2500

    // ---- layer 0 ----
    agg_mean<<<gb, 256, 0, stream>>>(xcat, offsets, counts, sorted, invc, rowss, NN);
    gemm_mfma<<<dim3(4, gyM), 256, 0, stream>>>(xcat, Wc0, b0, Cb, rowss, NN, 512);
    apply_scale<512, false><<<gb, 256, 0, stream>>>(Cb, rowss, xcat, nullptr, NN);
    // ---- layer 1 ----
    agg_mean<<<gb, 256, 0, stream>>>(xcat, offsets, counts, sorted, invc, rowss, NN);
    gemm_mfma<<<dim3(4, gyM), 256, 0, stream>>>(xcat, Wc1, b1, Cb, rowss, NN, 512);
    apply_scale<512, false><<<gb, 256, 0, stream>>>(Cb, rowss, xcat, nullptr, NN);
    // ---- layer 2 ----
    agg_mean<<<gb, 256, 0, stream>>>(xcat, offsets, counts, sorted, invc, rowss, NN);
    gemm_mfma<<<dim3(2, gyM), 256, 0, stream>>>(xcat, Wc2, b2, Cb, rowss, NN, 256);
    apply_scale<256, true><<<gb, 256, 0, stream>>>(Cb, rowss, nullptr, (float*)d_out, NN);
}